// Round 14
// baseline (144.650 us; speedup 1.0000x reference)
//
#include <hip/hip_runtime.h>

#define IN_C   128
#define HC     128   // HEADS*OUT_C
#define HEADS  4
#define NEG    0.2f

#define BSH    8     // bucket = dst >> 8  (256 nodes per bucket)
#define KMAX   512   // max buckets (n <= 131072)
#define EPB_F  2048  // edges per p1 branch block (512 threads x 4)
#define CAP    5120  // staged bucket capacity (mean 4096, sigma 64 -> 16 sigma)
#define CAPO   6144  // padded CSR bucket capacity (5120 + 768 pad + slack)

#define WT_STRIDE 136   // padded k-stride (ushorts) for transposed W

typedef __attribute__((ext_vector_type(8))) short short8;
typedef __attribute__((ext_vector_type(4))) float f32x4;

// bf16 helpers: xh stored packed, 2 channels per uint (ch 2j = low 16 bits).
__device__ __forceinline__ uint bf16_rne(float f) {
    uint u = __float_as_uint(f);
    return (u + 0x7FFFu + ((u >> 16) & 1u)) >> 16;
}
__device__ __forceinline__ uint pack_bf2(float even, float odd) {
    return bf16_rne(even) | (bf16_rne(odd) << 16);
}
__device__ __forceinline__ float bf_lo(uint u) { return __uint_as_float(u << 16); }
__device__ __forceinline__ float bf_hi(uint u) { return __uint_as_float(u & 0xFFFF0000u); }

// ---------------------------------------------------------------------------
// wprep: W[128][128] f32 -> wtb[col][k] bf16, k-stride 136 (pad zeroed).
// Also zeroes bucket counters AND initializes the dummy row n:
// xhb[n] = 0 (so dummy gathers contribute nothing, no NaN from poison),
// asrc[n*4+h] = -1e30 (so w = exp(-2e29) = 0).
// ---------------------------------------------------------------------------
__global__ __launch_bounds__(256) void wprep_kernel(
    const float* __restrict__ W, ushort* __restrict__ wtb,
    int* __restrict__ bcount, uint* __restrict__ xhb, float* __restrict__ asrc,
    int n)
{
    const int idx = blockIdx.x * 256 + threadIdx.x;
    if (idx < KMAX) bcount[idx] = 0;
    if (idx < 64)  xhb[(size_t)n * 64 + idx] = 0u;
    if (idx < 4)   asrc[(size_t)n * 4 + idx] = -1e30f;
    if (idx >= 128 * WT_STRIDE) return;
    const int col = idx / WT_STRIDE;
    const int k   = idx - col * WT_STRIDE;
    wtb[idx] = (k < 128) ? (ushort)bf16_rne(W[k * HC + col]) : (ushort)0;
}

// ---------------------------------------------------------------------------
// FUSED kernel: grid-partitioned. Even blocks -> GEMM branch (MFMA xh + logits),
// odd blocks -> P1 branch (edge partition into fixed-capacity buckets).
// ---------------------------------------------------------------------------
__global__ __launch_bounds__(512) void fused_gemm_p1_kernel(
    const float* __restrict__ x, const ushort* __restrict__ wtb,
    const float* __restrict__ att_src, const float* __restrict__ att_dst,
    ushort* __restrict__ xhb16, float* __restrict__ asrc, float* __restrict__ adst,
    const int* __restrict__ src, const int* __restrict__ dst,
    int* __restrict__ bcount, uint* __restrict__ staged,
    int n, int E)
{
    __shared__ __align__(16) char smem[128 * WT_STRIDE * 2];   // 34816 B union

    const int G = (n + 127) >> 7;              // gemm blocks
    const int P = (E + EPB_F - 1) / EPB_F;     // p1 blocks
    const int M = min(G, P);
    const int b = blockIdx.x;
    bool is_p1;
    int  idx;
    if (b < 2 * M) { is_p1 = (b & 1);  idx = b >> 1; }
    else           { is_p1 = (P > G);  idx = M + (b - 2 * M); }

    const int tid = threadIdx.x;

    if (!is_p1) {
        // =================== GEMM branch ===================
        ushort* Wt = (ushort*)smem;
        for (int i = tid; i < 128 * WT_STRIDE / 2; i += 512)
            ((uint*)Wt)[i] = ((const uint*)wtb)[i];
        __syncthreads();

        const int lane = tid & 63;
        const int wid  = tid >> 6;          // 0..7
        const int l15  = lane & 15;
        const int lk   = lane >> 4;         // 0..3
        const int row0 = idx * 128 + wid * 16;
        const uint arow = (uint)min(row0 + l15, n - 1);

        f32x4 acc[8];
#pragma unroll
        for (int ct = 0; ct < 8; ++ct) acc[ct] = (f32x4){0.f, 0.f, 0.f, 0.f};

#pragma unroll
        for (int kc = 0; kc < 4; ++kc) {
            const uint koff = kc * 32 + lk * 8;
            const float4 fa = *(const float4*)&x[arow * 128u + koff];
            const float4 fb = *(const float4*)&x[arow * 128u + koff + 4u];
            uint4 av = make_uint4(pack_bf2(fa.x, fa.y), pack_bf2(fa.z, fa.w),
                                  pack_bf2(fb.x, fb.y), pack_bf2(fb.z, fb.w));
            const short8 afrag = *(short8*)&av;
#pragma unroll
            for (int ct = 0; ct < 8; ++ct) {
                const int col = ct * 16 + l15;
                const short8 bfrag = *(const short8*)&Wt[col * WT_STRIDE + koff];
                acc[ct] = __builtin_amdgcn_mfma_f32_16x16x32_bf16(
                    afrag, bfrag, acc[ct], 0, 0, 0);
            }
        }

        float as_lo[4], as_hi[4], ad_lo[4], ad_hi[4];
#pragma unroll
        for (int h = 0; h < 4; ++h) {
            as_lo[h] = att_src[h * 32 + l15];
            as_hi[h] = att_src[h * 32 + 16 + l15];
            ad_lo[h] = att_dst[h * 32 + l15];
            ad_hi[h] = att_dst[h * 32 + 16 + l15];
        }

#pragma unroll
        for (int reg = 0; reg < 4; ++reg) {
            const int r = row0 + lk * 4 + reg;
            const bool ok = r < n;
            if (ok) {
#pragma unroll
                for (int ct = 0; ct < 8; ++ct)
                    xhb16[(uint)r * 128u + ct * 16 + l15] =
                        (ushort)bf16_rne(acc[ct][reg]);
            }
            float p0 = acc[0][reg] * as_lo[0] + acc[1][reg] * as_hi[0];
            float p1 = acc[2][reg] * as_lo[1] + acc[3][reg] * as_hi[1];
            float p2 = acc[4][reg] * as_lo[2] + acc[5][reg] * as_hi[2];
            float p3 = acc[6][reg] * as_lo[3] + acc[7][reg] * as_hi[3];
            float q0 = acc[0][reg] * ad_lo[0] + acc[1][reg] * ad_hi[0];
            float q1 = acc[2][reg] * ad_lo[1] + acc[3][reg] * ad_hi[1];
            float q2 = acc[4][reg] * ad_lo[2] + acc[5][reg] * ad_hi[2];
            float q3 = acc[6][reg] * ad_lo[3] + acc[7][reg] * ad_hi[3];
#pragma unroll
            for (int m = 1; m < 16; m <<= 1) {
                p0 += __shfl_xor(p0, m); p1 += __shfl_xor(p1, m);
                p2 += __shfl_xor(p2, m); p3 += __shfl_xor(p3, m);
                q0 += __shfl_xor(q0, m); q1 += __shfl_xor(q1, m);
                q2 += __shfl_xor(q2, m); q3 += __shfl_xor(q3, m);
            }
            if (l15 == 0 && ok) {
                *(float4*)&asrc[(uint)r * 4u] = make_float4(p0, p1, p2, p3);
                *(float4*)&adst[(uint)r * 4u] = make_float4(q0, q1, q2, q3);
            }
        }
    } else {
        // =================== P1 branch (512 threads) ===================
        int*   hist  = (int*)smem;            // 512
        int*   lbase = hist  + KMAX;          // 512
        int*   gbase = lbase + KMAX;          // 512
        int*   lcur  = gbase + KMAX;          // 512
        int*   sd    = lcur  + KMAX;          // 512
        uint2* stage = (uint2*)(sd + KMAX);   // 2048 x 8B = 16 KiB

        const int t = tid;                    // 0..511
        hist[t] = 0;
        __syncthreads();

        const int base = idx * EPB_F;
        uint sv[EPB_F / 512], dv[EPB_F / 512];
#pragma unroll
        for (int i = 0; i < EPB_F / 512; ++i) {
            const int e = base + i * 512 + t;
            if (e < E) {
                sv[i] = (uint)src[e];
                dv[i] = (uint)dst[e];
                atomicAdd(&hist[dv[i] >> BSH], 1);
            } else {
                dv[i] = 0xFFFFFFFFu;
            }
        }
        __syncthreads();

        // exclusive scan of hist[512] (one bucket per thread)
        const int h0 = hist[t];
        sd[t] = h0;
        __syncthreads();
#pragma unroll
        for (int off = 1; off < 512; off <<= 1) {
            const int v = (t >= off) ? sd[t - off] : 0;
            __syncthreads();
            sd[t] += v;
            __syncthreads();
        }
        const int excl = t ? sd[t - 1] : 0;
        lbase[t] = excl;
        lcur[t]  = excl;
        gbase[t] = h0 ? t * CAP + atomicAdd(&bcount[t], h0) : 0;
        __syncthreads();

        // place edges into LDS staging, grouped by bucket
#pragma unroll
        for (int i = 0; i < EPB_F / 512; ++i) {
            if (dv[i] != 0xFFFFFFFFu) {
                const int slot = atomicAdd(&lcur[dv[i] >> BSH], 1);
                stage[slot] = make_uint2(sv[i], dv[i]);
            }
        }
        __syncthreads();

        // bucket-contiguous packed write-out
        const int total = sd[KMAX - 1];
        for (int j = t; j < total; j += 512) {
            const uint2 ev = stage[j];
            const int bb = ev.y >> BSH;
            staged[gbase[bb] + (j - lbase[bb])] = ((ev.y & 255u) << 24) | ev.x;
        }
    }
}

// ---------------------------------------------------------------------------
// P2: one WG per bucket, single staged read; register-cached entries,
// LDS histogram + scan (of 4-PADDED degrees), scatter, pad each node's list
// to a multiple of 4 with dummy index n, +4 tail dummies per bucket (keeps
// the aggregate's one-ahead prefetch in initialized memory), coalesced write.
// deg_out = PADDED degree (aggregate loop bound; dummies carry weight 0).
// ---------------------------------------------------------------------------
__global__ __launch_bounds__(256) void p2_csr_kernel(
    const uint* __restrict__ staged, const int* __restrict__ bcount,
    int* __restrict__ csr_src, int* __restrict__ node_beg,
    int* __restrict__ deg_out, int n)
{
    __shared__ int deg[256];
    __shared__ int cur[256];
    __shared__ int sd[256];
    __shared__ int sorted[CAPO];   // 24 KiB
    const int b  = blockIdx.x;
    const int t  = threadIdx.x;
    const int sb = b * CAP;        // staged base
    const int eb = b * CAPO;       // padded CSR base
    const int cnt = min(bcount[b], CAP);   // CAP = 20*256 exactly
    const int v0 = b << BSH;

    deg[t] = 0;
    __syncthreads();

    uint val[CAP / 256];
#pragma unroll
    for (int j = 0; j < CAP / 256; ++j) {
        const int i = j * 256 + t;
        val[j] = (i < cnt) ? staged[sb + i] : 0xFFFFFFFFu;  // src<2^17 => never
        if (val[j] != 0xFFFFFFFFu) atomicAdd(&deg[val[j] >> 24], 1);
    }
    __syncthreads();

    const int d  = deg[t];
    const int pd = (d + 3) & ~3;           // padded to multiple of 4
    sd[t] = pd;
    __syncthreads();
#pragma unroll
    for (int off = 1; off < 256; off <<= 1) {
        const int v = (t >= off) ? sd[t - off] : 0;
        __syncthreads();
        sd[t] += v;
        __syncthreads();
    }
    const int excl = t ? sd[t - 1] : 0;
    cur[t] = excl;
    if (v0 + t < n) {
        node_beg[v0 + t] = eb + excl;
        deg_out[v0 + t]  = pd;
    }
    __syncthreads();

#pragma unroll
    for (int j = 0; j < CAP / 256; ++j) {
        if (val[j] != 0xFFFFFFFFu) {
            const int slot = atomicAdd(&cur[val[j] >> 24], 1);
            sorted[slot] = (int)(val[j] & 0x00FFFFFFu);
        }
    }
    __syncthreads();

    // pad this thread's node to its padded degree with the dummy row n
    for (int k = excl + d; k < excl + pd; ++k) sorted[k] = n;
    const int total = sd[255];
    if (t < 4) sorted[total + t] = n;      // tail dummies for prefetch
    __syncthreads();

    for (int i = t; i < total + 4; i += 256)
        csr_src[eb + i] = sorted[i];
}

// ---------------------------------------------------------------------------
// Fused aggregate v6: one wave per dst node, 4 edges/iter, 2-deep pipeline,
// SELECT-FREE inner loop: CSR is padded to x4 with dummy row n (w=0, row=0),
// so no bounds compares or cndmasks anywhere in the steady state.
// ---------------------------------------------------------------------------
__global__ __launch_bounds__(256) void aggregate_csr_kernel(
    const int* __restrict__ csr_src, const int* __restrict__ node_beg,
    const int* __restrict__ deg,
    const float* __restrict__ asrc, const float* __restrict__ adst,
    const uint* __restrict__ xhb, const float* __restrict__ bias,
    float* __restrict__ out, int n)
{
    const int node = blockIdx.x * 4 + (threadIdx.x >> 6);
    if (node >= n) return;
    const int  lane = threadIdx.x & 63;
    const int  sub  = lane >> 4;       // subgroup: which of 4 edges
    const uint l16  = lane & 15;       // lane within subgroup
    const uint h    = l16 >> 2;        // head 0..3
    const uint coff = l16 * 4u;        // uint offset of this lane's uint4

    const int beg = node_beg[node];
    const int end = beg + deg[node];   // padded degree (multiple of 4)

    const float adh = adst[(uint)node * 4u + h];

    // self-loop (subgroup 0 only; others contribute 0)
    const float zs = asrc[(uint)node * 4u + h] + adh;
    const float ws = (sub == 0) ? __expf(fmaxf(zs, NEG * zs)) : 0.f;
    const uint4 xs = *(const uint4*)&xhb[(uint)node * 64u + coff];
    float acc[8];
    acc[0] = ws * bf_lo(xs.x); acc[1] = ws * bf_hi(xs.x);
    acc[2] = ws * bf_lo(xs.y); acc[3] = ws * bf_hi(xs.y);
    acc[4] = ws * bf_lo(xs.z); acc[5] = ws * bf_hi(xs.z);
    acc[6] = ws * bf_lo(xs.w); acc[7] = ws * bf_hi(xs.w);
    float ssum = ws;

    if (beg < end) {
        // ---- prologue: stage 0 loads (always valid; padded) ----
        uint s0  = (uint)csr_src[beg + sub];
        float a0 = asrc[s0 * 4u + h];
        uint4 x0 = *(const uint4*)&xhb[s0 * 64u + coff];

        for (int e = beg; e < end; e += 4) {
            // ---- issue stage 1 loads (tail dummies keep this in-bounds) ----
            const uint s1  = (uint)csr_src[e + 4 + sub];
            const float a1 = asrc[s1 * 4u + h];
            const uint4 x1 = *(const uint4*)&xhb[s1 * 64u + coff];

            // ---- consume stage 0 (dummy entries: a0=-1e30 -> w=0, x0=0) ----
            const float z = a0 + adh;
            const float w = __expf(fmaxf(z, NEG * z));
            acc[0] = fmaf(w, bf_lo(x0.x), acc[0]);
            acc[1] = fmaf(w, bf_hi(x0.x), acc[1]);
            acc[2] = fmaf(w, bf_lo(x0.y), acc[2]);
            acc[3] = fmaf(w, bf_hi(x0.y), acc[3]);
            acc[4] = fmaf(w, bf_lo(x0.z), acc[4]);
            acc[5] = fmaf(w, bf_hi(x0.z), acc[5]);
            acc[6] = fmaf(w, bf_lo(x0.w), acc[6]);
            acc[7] = fmaf(w, bf_hi(x0.w), acc[7]);
            ssum += w;

            a0 = a1; x0 = x1;
        }
    }

    // cross-subgroup reduction (4 partial sums at stride 16)
    ssum += __shfl_xor(ssum, 16);
    ssum += __shfl_xor(ssum, 32);
#pragma unroll
    for (int j = 0; j < 8; ++j) {
        acc[j] += __shfl_xor(acc[j], 16);
        acc[j] += __shfl_xor(acc[j], 32);
    }

    if (sub == 0) {
        const float inv = 1.f / ssum;
        const uint  c   = l16 * 8u;
        const float4 b0 = *(const float4*)&bias[c];
        const float4 b1 = *(const float4*)&bias[c + 4];
        float4 o0, o1;
        o0.x = fmaf(acc[0], inv, b0.x); o0.y = fmaf(acc[1], inv, b0.y);
        o0.z = fmaf(acc[2], inv, b0.z); o0.w = fmaf(acc[3], inv, b0.w);
        o1.x = fmaf(acc[4], inv, b1.x); o1.y = fmaf(acc[5], inv, b1.y);
        o1.z = fmaf(acc[6], inv, b1.z); o1.w = fmaf(acc[7], inv, b1.w);
        o0.x = fmaxf(o0.x, 0.f); o0.y = fmaxf(o0.y, 0.f);
        o0.z = fmaxf(o0.z, 0.f); o0.w = fmaxf(o0.w, 0.f);
        o1.x = fmaxf(o1.x, 0.f); o1.y = fmaxf(o1.y, 0.f);
        o1.z = fmaxf(o1.z, 0.f); o1.w = fmaxf(o1.w, 0.f);
        *(float4*)&out[(uint)node * 128u + c]      = o0;
        *(float4*)&out[(uint)node * 128u + c + 4u] = o1;
    }
}

// ---------------------------------------------------------------------------
extern "C" void kernel_launch(void* const* d_in, const int* in_sizes, int n_in,
                              void* d_out, int out_size, void* d_ws, size_t ws_size,
                              hipStream_t stream)
{
    const float* x       = (const float*)d_in[0];
    const int*   ei      = (const int*)d_in[1];   // [2,E] flat: src then dst
    const float* W       = (const float*)d_in[2];
    const float* att_src = (const float*)d_in[3];
    const float* att_dst = (const float*)d_in[4];
    const float* bias    = (const float*)d_in[5];

    const int n = in_sizes[0] / IN_C;
    const int E = in_sizes[1] / 2;
    const int* src = ei;
    const int* dst = ei + E;

    float* out = (float*)d_out;

    // workspace layout (4-byte units); xhb/asrc have a dummy row n appended
    uint*  xhb       = (uint*)d_ws;                        // (n+1)*64  (25.6MB)
    float* asrc      = (float*)(xhb + (size_t)(n + 1) * 64);  // (n+1)*4
    float* adst      = asrc + (size_t)(n + 1) * HEADS;     // n*4
    int*   node_beg  = (int*)(adst + (size_t)n * HEADS);   // n
    int*   deg       = node_beg + n;                       // n
    int*   bcount    = deg + n;                            // 512
    uint*  staged    = (uint*)(bcount + 512);              // 512*CAP   (10.5MB)
    int*   csr_src   = (int*)(staged + (size_t)KMAX * CAP);// 512*CAPO  (12.6MB)
    ushort* wtb      = (ushort*)(csr_src + (size_t)KMAX * CAPO); // 128*136

    const int K  = (n + 255) >> BSH;               // buckets
    const int G  = (n + 127) >> 7;                 // gemm blocks
    const int P  = (E + EPB_F - 1) / EPB_F;        // p1 blocks

    wprep_kernel<<<(128 * WT_STRIDE + 255) / 256, 256, 0, stream>>>(
        W, wtb, bcount, xhb, asrc, n);
    fused_gemm_p1_kernel<<<G + P, 512, 0, stream>>>(
        x, wtb, att_src, att_dst, (ushort*)xhb, asrc, adst,
        src, dst, bcount, staged, n, E);
    p2_csr_kernel<<<K, 256, 0, stream>>>(staged, bcount,
                                         csr_src, node_beg, deg, n);
    aggregate_csr_kernel<<<(n + 3) / 4, 256, 0, stream>>>(csr_src, node_beg, deg,
                                                          asrc, adst, xhb, bias,
                                                          out, n);
}

// Round 15
// 140.708 us; speedup vs baseline: 1.0280x; 1.0280x over previous
//
#include <hip/hip_runtime.h>

#define IN_C   128
#define HC     128   // HEADS*OUT_C
#define HEADS  4
#define NEG    0.2f

#define BSH    8     // bucket = dst >> 8  (256 nodes per bucket)
#define KMAX   512   // max buckets (n <= 131072)
#define EPB_F  2048  // edges per p1 branch block (512 threads x 4)
#define CAP    5120  // fixed bucket capacity (mean 4096, sigma 64 -> 16 sigma)

#define WT_STRIDE 136   // padded k-stride (ushorts) for transposed W

typedef __attribute__((ext_vector_type(8))) short short8;
typedef __attribute__((ext_vector_type(4))) float f32x4;

// bf16 helpers: xh stored packed, 2 channels per uint (ch 2j = low 16 bits).
__device__ __forceinline__ uint bf16_rne(float f) {
    uint u = __float_as_uint(f);
    return (u + 0x7FFFu + ((u >> 16) & 1u)) >> 16;
}
__device__ __forceinline__ uint pack_bf2(float even, float odd) {
    return bf16_rne(even) | (bf16_rne(odd) << 16);
}
__device__ __forceinline__ float bf_lo(uint u) { return __uint_as_float(u << 16); }
__device__ __forceinline__ float bf_hi(uint u) { return __uint_as_float(u & 0xFFFF0000u); }

// ---------------------------------------------------------------------------
// wprep: W[128][128] f32 -> wtb[col][k] bf16, k-stride 136 (pad zeroed).
// Also zeroes the 512 bucket counters.
// ---------------------------------------------------------------------------
__global__ __launch_bounds__(256) void wprep_kernel(
    const float* __restrict__ W, ushort* __restrict__ wtb,
    int* __restrict__ bcount)
{
    const int idx = blockIdx.x * 256 + threadIdx.x;
    if (idx < KMAX) bcount[idx] = 0;
    if (idx >= 128 * WT_STRIDE) return;
    const int col = idx / WT_STRIDE;
    const int k   = idx - col * WT_STRIDE;
    wtb[idx] = (k < 128) ? (ushort)bf16_rne(W[k * HC + col]) : (ushort)0;
}

// ---------------------------------------------------------------------------
// FUSED kernel: grid-partitioned. Even blocks -> GEMM branch (MFMA xh + logits),
// odd blocks -> P1 branch (edge partition into fixed-capacity buckets).
// The two branches have no data dependence; fusing overlaps gemm's MFMA/VMEM
// work with p1's LDS-atomic work instead of running them serially.
// Shared-LDS union: gemm Wt (34816 B) >= p1 (26624 B).
// ---------------------------------------------------------------------------
__global__ __launch_bounds__(512) void fused_gemm_p1_kernel(
    const float* __restrict__ x, const ushort* __restrict__ wtb,
    const float* __restrict__ att_src, const float* __restrict__ att_dst,
    ushort* __restrict__ xhb16, float* __restrict__ asrc, float* __restrict__ adst,
    const int* __restrict__ src, const int* __restrict__ dst,
    int* __restrict__ bcount, uint* __restrict__ staged,
    int n, int E)
{
    __shared__ __align__(16) char smem[128 * WT_STRIDE * 2];   // 34816 B union

    const int G = (n + 127) >> 7;              // gemm blocks
    const int P = (E + EPB_F - 1) / EPB_F;     // p1 blocks
    const int M = min(G, P);
    const int b = blockIdx.x;
    bool is_p1;
    int  idx;
    if (b < 2 * M) { is_p1 = (b & 1);  idx = b >> 1; }
    else           { is_p1 = (P > G);  idx = M + (b - 2 * M); }

    const int tid = threadIdx.x;

    if (!is_p1) {
        // =================== GEMM branch ===================
        ushort* Wt = (ushort*)smem;
        for (int i = tid; i < 128 * WT_STRIDE / 2; i += 512)
            ((uint*)Wt)[i] = ((const uint*)wtb)[i];
        __syncthreads();

        const int lane = tid & 63;
        const int wid  = tid >> 6;          // 0..7
        const int l15  = lane & 15;
        const int lk   = lane >> 4;         // 0..3
        const int row0 = idx * 128 + wid * 16;
        const uint arow = (uint)min(row0 + l15, n - 1);

        f32x4 acc[8];
#pragma unroll
        for (int ct = 0; ct < 8; ++ct) acc[ct] = (f32x4){0.f, 0.f, 0.f, 0.f};

#pragma unroll
        for (int kc = 0; kc < 4; ++kc) {
            const uint koff = kc * 32 + lk * 8;
            const float4 fa = *(const float4*)&x[arow * 128u + koff];
            const float4 fb = *(const float4*)&x[arow * 128u + koff + 4u];
            uint4 av = make_uint4(pack_bf2(fa.x, fa.y), pack_bf2(fa.z, fa.w),
                                  pack_bf2(fb.x, fb.y), pack_bf2(fb.z, fb.w));
            const short8 afrag = *(short8*)&av;
#pragma unroll
            for (int ct = 0; ct < 8; ++ct) {
                const int col = ct * 16 + l15;
                const short8 bfrag = *(const short8*)&Wt[col * WT_STRIDE + koff];
                acc[ct] = __builtin_amdgcn_mfma_f32_16x16x32_bf16(
                    afrag, bfrag, acc[ct], 0, 0, 0);
            }
        }

        float as_lo[4], as_hi[4], ad_lo[4], ad_hi[4];
#pragma unroll
        for (int h = 0; h < 4; ++h) {
            as_lo[h] = att_src[h * 32 + l15];
            as_hi[h] = att_src[h * 32 + 16 + l15];
            ad_lo[h] = att_dst[h * 32 + l15];
            ad_hi[h] = att_dst[h * 32 + 16 + l15];
        }

#pragma unroll
        for (int reg = 0; reg < 4; ++reg) {
            const int r = row0 + lk * 4 + reg;
            const bool ok = r < n;
            if (ok) {
#pragma unroll
                for (int ct = 0; ct < 8; ++ct)
                    xhb16[(uint)r * 128u + ct * 16 + l15] =
                        (ushort)bf16_rne(acc[ct][reg]);
            }
            float p0 = acc[0][reg] * as_lo[0] + acc[1][reg] * as_hi[0];
            float p1 = acc[2][reg] * as_lo[1] + acc[3][reg] * as_hi[1];
            float p2 = acc[4][reg] * as_lo[2] + acc[5][reg] * as_hi[2];
            float p3 = acc[6][reg] * as_lo[3] + acc[7][reg] * as_hi[3];
            float q0 = acc[0][reg] * ad_lo[0] + acc[1][reg] * ad_hi[0];
            float q1 = acc[2][reg] * ad_lo[1] + acc[3][reg] * ad_hi[1];
            float q2 = acc[4][reg] * ad_lo[2] + acc[5][reg] * ad_hi[2];
            float q3 = acc[6][reg] * ad_lo[3] + acc[7][reg] * ad_hi[3];
#pragma unroll
            for (int m = 1; m < 16; m <<= 1) {
                p0 += __shfl_xor(p0, m); p1 += __shfl_xor(p1, m);
                p2 += __shfl_xor(p2, m); p3 += __shfl_xor(p3, m);
                q0 += __shfl_xor(q0, m); q1 += __shfl_xor(q1, m);
                q2 += __shfl_xor(q2, m); q3 += __shfl_xor(q3, m);
            }
            if (l15 == 0 && ok) {
                *(float4*)&asrc[(uint)r * 4u] = make_float4(p0, p1, p2, p3);
                *(float4*)&adst[(uint)r * 4u] = make_float4(q0, q1, q2, q3);
            }
        }
    } else {
        // =================== P1 branch (512 threads) ===================
        int*   hist  = (int*)smem;            // 512
        int*   lbase = hist  + KMAX;          // 512
        int*   gbase = lbase + KMAX;          // 512
        int*   lcur  = gbase + KMAX;          // 512
        int*   sd    = lcur  + KMAX;          // 512
        uint2* stage = (uint2*)(sd + KMAX);   // 2048 x 8B = 16 KiB

        const int t = tid;                    // 0..511
        hist[t] = 0;
        __syncthreads();

        const int base = idx * EPB_F;
        uint sv[EPB_F / 512], dv[EPB_F / 512];
#pragma unroll
        for (int i = 0; i < EPB_F / 512; ++i) {
            const int e = base + i * 512 + t;
            if (e < E) {
                sv[i] = (uint)src[e];
                dv[i] = (uint)dst[e];
                atomicAdd(&hist[dv[i] >> BSH], 1);
            } else {
                dv[i] = 0xFFFFFFFFu;
            }
        }
        __syncthreads();

        // exclusive scan of hist[512] (one bucket per thread)
        const int h0 = hist[t];
        sd[t] = h0;
        __syncthreads();
#pragma unroll
        for (int off = 1; off < 512; off <<= 1) {
            const int v = (t >= off) ? sd[t - off] : 0;
            __syncthreads();
            sd[t] += v;
            __syncthreads();
        }
        const int excl = t ? sd[t - 1] : 0;
        lbase[t] = excl;
        lcur[t]  = excl;
        gbase[t] = h0 ? t * CAP + atomicAdd(&bcount[t], h0) : 0;
        __syncthreads();

        // place edges into LDS staging, grouped by bucket
#pragma unroll
        for (int i = 0; i < EPB_F / 512; ++i) {
            if (dv[i] != 0xFFFFFFFFu) {
                const int slot = atomicAdd(&lcur[dv[i] >> BSH], 1);
                stage[slot] = make_uint2(sv[i], dv[i]);
            }
        }
        __syncthreads();

        // bucket-contiguous packed write-out
        const int total = sd[KMAX - 1];
        for (int j = t; j < total; j += 512) {
            const uint2 ev = stage[j];
            const int bb = ev.y >> BSH;
            staged[gbase[bb] + (j - lbase[bb])] = ((ev.y & 255u) << 24) | ev.x;
        }
    }
}

// ---------------------------------------------------------------------------
// P2: one WG per bucket, single staged read; register-cached entries,
// LDS histogram + scan, scatter, coalesced csr_src write.
// ---------------------------------------------------------------------------
__global__ __launch_bounds__(256) void p2_csr_kernel(
    const uint* __restrict__ staged, const int* __restrict__ bcount,
    int* __restrict__ csr_src, int* __restrict__ node_beg,
    int* __restrict__ deg_out, int n)
{
    __shared__ int deg[256];
    __shared__ int cur[256];
    __shared__ int sd[256];
    __shared__ int sorted[CAP];   // 20 KiB
    const int b  = blockIdx.x;
    const int t  = threadIdx.x;
    const int eb = b * CAP;
    const int cnt = min(bcount[b], CAP);   // CAP = 20*256 exactly
    const int v0 = b << BSH;

    deg[t] = 0;
    __syncthreads();

    uint val[CAP / 256];
#pragma unroll
    for (int j = 0; j < CAP / 256; ++j) {
        const int i = j * 256 + t;
        val[j] = (i < cnt) ? staged[eb + i] : 0xFFFFFFFFu;  // src<2^17 => never
        if (val[j] != 0xFFFFFFFFu) atomicAdd(&deg[val[j] >> 24], 1);
    }
    __syncthreads();

    const int d = deg[t];
    sd[t] = d;
    __syncthreads();
#pragma unroll
    for (int off = 1; off < 256; off <<= 1) {
        const int v = (t >= off) ? sd[t - off] : 0;
        __syncthreads();
        sd[t] += v;
        __syncthreads();
    }
    const int excl = t ? sd[t - 1] : 0;
    cur[t] = excl;
    if (v0 + t < n) {
        node_beg[v0 + t] = eb + excl;
        deg_out[v0 + t]  = d;
    }
    __syncthreads();

#pragma unroll
    for (int j = 0; j < CAP / 256; ++j) {
        if (val[j] != 0xFFFFFFFFu) {
            const int slot = atomicAdd(&cur[val[j] >> 24], 1);
            sorted[slot] = (int)(val[j] & 0x00FFFFFFu);
        }
    }
    __syncthreads();

    for (int i = t; i < cnt; i += 256)
        csr_src[eb + i] = sorted[i];
}

// ---------------------------------------------------------------------------
// Fused aggregate (round-8 best): one wave per dst node, 4 edges/iter,
// pipelined 2 deep (8 edges / 2x256B rows in flight per wave).
// ---------------------------------------------------------------------------
__global__ __launch_bounds__(256) void aggregate_csr_kernel(
    const int* __restrict__ csr_src, const int* __restrict__ node_beg,
    const int* __restrict__ deg,
    const float* __restrict__ asrc, const float* __restrict__ adst,
    const uint* __restrict__ xhb, const float* __restrict__ bias,
    float* __restrict__ out, int n)
{
    const int node = blockIdx.x * 4 + (threadIdx.x >> 6);
    if (node >= n) return;
    const int  lane = threadIdx.x & 63;
    const int  sub  = lane >> 4;       // subgroup: which of 4 edges
    const uint l16  = lane & 15;       // lane within subgroup
    const uint h    = l16 >> 2;        // head 0..3
    const uint coff = l16 * 4u;        // uint offset of this lane's uint4

    const int beg = node_beg[node];
    const int end = beg + deg[node];

    const float adh = adst[(uint)node * 4u + h];

    // self-loop (subgroup 0 only; others contribute 0)
    const float zs = asrc[(uint)node * 4u + h] + adh;
    const float ws = (sub == 0) ? __expf(fmaxf(zs, NEG * zs)) : 0.f;
    const uint4 xs = *(const uint4*)&xhb[(uint)node * 64u + coff];
    float acc[8];
    acc[0] = ws * bf_lo(xs.x); acc[1] = ws * bf_hi(xs.x);
    acc[2] = ws * bf_lo(xs.y); acc[3] = ws * bf_hi(xs.y);
    acc[4] = ws * bf_lo(xs.z); acc[5] = ws * bf_hi(xs.z);
    acc[6] = ws * bf_lo(xs.w); acc[7] = ws * bf_hi(xs.w);
    float ssum = ws;

    if (beg < end) {
        // ---- prologue: stage 0 loads ----
        int  eg0 = beg + sub;
        bool v0  = eg0 < end;
        uint s0  = v0 ? (uint)csr_src[eg0] : (uint)node;
        float a0 = asrc[s0 * 4u + h];
        uint4 x0 = *(const uint4*)&xhb[s0 * 64u + coff];

        for (int e = beg; e < end; e += 4) {
            // ---- issue stage 1 (next chunk) loads first ----
            const int  eg1 = e + 4 + sub;
            const bool v1  = eg1 < end;
            const uint s1  = v1 ? (uint)csr_src[eg1] : (uint)node;
            const float a1 = asrc[s1 * 4u + h];
            const uint4 x1 = *(const uint4*)&xhb[s1 * 64u + coff];

            // ---- consume stage 0 ----
            const float z = a0 + adh;
            float w = __expf(fmaxf(z, NEG * z));
            w = v0 ? w : 0.f;
            acc[0] = fmaf(w, bf_lo(x0.x), acc[0]);
            acc[1] = fmaf(w, bf_hi(x0.x), acc[1]);
            acc[2] = fmaf(w, bf_lo(x0.y), acc[2]);
            acc[3] = fmaf(w, bf_hi(x0.y), acc[3]);
            acc[4] = fmaf(w, bf_lo(x0.z), acc[4]);
            acc[5] = fmaf(w, bf_hi(x0.z), acc[5]);
            acc[6] = fmaf(w, bf_lo(x0.w), acc[6]);
            acc[7] = fmaf(w, bf_hi(x0.w), acc[7]);
            ssum += w;

            v0 = v1; a0 = a1; x0 = x1;
        }
    }

    // cross-subgroup reduction (4 partial sums at stride 16)
    ssum += __shfl_xor(ssum, 16);
    ssum += __shfl_xor(ssum, 32);
#pragma unroll
    for (int j = 0; j < 8; ++j) {
        acc[j] += __shfl_xor(acc[j], 16);
        acc[j] += __shfl_xor(acc[j], 32);
    }

    if (sub == 0) {
        const float inv = 1.f / ssum;
        const uint  c   = l16 * 8u;
        const float4 b0 = *(const float4*)&bias[c];
        const float4 b1 = *(const float4*)&bias[c + 4];
        float4 o0, o1;
        o0.x = fmaf(acc[0], inv, b0.x); o0.y = fmaf(acc[1], inv, b0.y);
        o0.z = fmaf(acc[2], inv, b0.z); o0.w = fmaf(acc[3], inv, b0.w);
        o1.x = fmaf(acc[4], inv, b1.x); o1.y = fmaf(acc[5], inv, b1.y);
        o1.z = fmaf(acc[6], inv, b1.z); o1.w = fmaf(acc[7], inv, b1.w);
        o0.x = fmaxf(o0.x, 0.f); o0.y = fmaxf(o0.y, 0.f);
        o0.z = fmaxf(o0.z, 0.f); o0.w = fmaxf(o0.w, 0.f);
        o1.x = fmaxf(o1.x, 0.f); o1.y = fmaxf(o1.y, 0.f);
        o1.z = fmaxf(o1.z, 0.f); o1.w = fmaxf(o1.w, 0.f);
        *(float4*)&out[(uint)node * 128u + c]      = o0;
        *(float4*)&out[(uint)node * 128u + c + 4u] = o1;
    }
}

// ---------------------------------------------------------------------------
extern "C" void kernel_launch(void* const* d_in, const int* in_sizes, int n_in,
                              void* d_out, int out_size, void* d_ws, size_t ws_size,
                              hipStream_t stream)
{
    const float* x       = (const float*)d_in[0];
    const int*   ei      = (const int*)d_in[1];   // [2,E] flat: src then dst
    const float* W       = (const float*)d_in[2];
    const float* att_src = (const float*)d_in[3];
    const float* att_dst = (const float*)d_in[4];
    const float* bias    = (const float*)d_in[5];

    const int n = in_sizes[0] / IN_C;
    const int E = in_sizes[1] / 2;
    const int* src = ei;
    const int* dst = ei + E;

    float* out = (float*)d_out;

    // workspace layout (4-byte units)
    uint*  xhb       = (uint*)d_ws;                        // n*64      (25.6MB)
    float* asrc      = (float*)(xhb + (size_t)n * 64);     // n*4
    float* adst      = asrc + (size_t)n * HEADS;           // n*4
    int*   node_beg  = (int*)(adst + (size_t)n * HEADS);   // n
    int*   deg       = node_beg + n;                       // n
    int*   bcount    = deg + n;                            // 512
    uint*  staged    = (uint*)(bcount + 512);              // 512*CAP   (10.5MB)
    int*   csr_src   = (int*)(staged + (size_t)KMAX * CAP);// 512*CAP   (10.5MB)
    ushort* wtb      = (ushort*)(csr_src + (size_t)KMAX * CAP); // 128*136

    const int K  = (n + 255) >> BSH;               // buckets
    const int G  = (n + 127) >> 7;                 // gemm blocks
    const int P  = (E + EPB_F - 1) / EPB_F;        // p1 blocks

    wprep_kernel<<<(128 * WT_STRIDE + 255) / 256, 256, 0, stream>>>(W, wtb, bcount);
    fused_gemm_p1_kernel<<<G + P, 512, 0, stream>>>(
        x, wtb, att_src, att_dst, (ushort*)xhb, asrc, adst,
        src, dst, bcount, staged, n, E);
    p2_csr_kernel<<<K, 256, 0, stream>>>(staged, bcount,
                                         csr_src, node_beg, deg, n);
    aggregate_csr_kernel<<<(n + 3) / 4, 256, 0, stream>>>(csr_src, node_beg, deg,
                                                          asrc, adst, xhb, bias,
                                                          out, n);
}